// Round 1
// baseline (275.709 us; speedup 1.0000x reference)
//
#include <hip/hip_runtime.h>

// SAR-ADC 4-bit successive-approximation quantizer.
// Element-wise over N = LENGTH*NADC = 12M floats. Memory-bound:
//   read x (48 MB), write q (48 MB) + Q (192 MB)  -> ~46 us at 6.3 TB/s.
//
// V2: grid-stride streamer. The one-shot version (1 load + 2 stores per
// wave lifetime, 6 KB traffic per block) ran at ~2.4 TB/s effective vs the
// rocclr fill's 6.58 TB/s on the same chip. Restructured so each thread
// handles 4 elements (base + t + 256k) across ~5.7 chunks per block:
//  - every access stays unit-stride per instruction (x/q 4B/lane,
//    Q float4 16B/lane),
//  - 4 independent x loads in flight per wave iteration (4x MLP),
//  - W s_loads + prologue amortized over ~23x more traffic.
//
// Numerics: reference does float32 ops throughout. (Q+1)*0.5 is exactly
// 0.0 or 1.0, so each bit_sum = fl(W[m]*VREF) + subset of fl(W[k]*VR),
// added in the reference's fixed order. __fmul_rn/__fadd_rn prevent FMA
// contraction -> bit-exact thresholds -> bit-exact sign decisions.
// sign(x - b + 1e-30) == (x >= b ? +1 : -1): nonzero diffs are >= ~1e-9
// (both operands on coarse float grids), so DELTA only rescues diff==0.

#define BLOCK 256
#define ELEMS_PER_THREAD 4
#define ELEMS_PER_BLOCK (BLOCK * ELEMS_PER_THREAD)   // 1024

__global__ __launch_bounds__(BLOCK)
void sar_adc_kernel(const float* __restrict__ x, const float* __restrict__ W,
                    float* __restrict__ q_out, float* __restrict__ Q_out, int n)
{
    const float VREF = 0.1125f;   // fl32(1.8/16) == fl32(0.1125)
    const float VR   = 0.1125f;

    // Wave-uniform W loads (compiler lifts to s_load); hoisted out of the
    // grid-stride loop so they are paid once per wave.
    float w0 = W[0], w1 = W[1], w2 = W[2], w3 = W[3], w4 = W[4];
    float w5 = W[5], w6 = W[6], w7 = W[7], w8 = W[8], w9 = W[9];

    // Precompute fl(W[k]*VR) terms (exactly what the reference's
    // (Q+1)*0.5*W[k]*VR evaluates to when the bit is set).
    float wv0 = __fmul_rn(w0, VR);
    float wv1 = __fmul_rn(w1, VR);
    float wv2 = __fmul_rn(w2, VR);
    float wv4 = __fmul_rn(w4, VR);
    float wv5 = __fmul_rn(w5, VR);
    float wv7 = __fmul_rn(w7, VR);
    float b3  = __fmul_rn(w9, VREF);   // j=3 threshold (no bit terms)
    float b2r = __fmul_rn(w8, VREF);   // j=2 base
    float b1r = __fmul_rn(w6, VREF);   // j=1 base
    float b0r = __fmul_rn(w3, VREF);   // j=0 base

    const float bw0 = 0.1125f, bw1 = 0.225f, bw2 = 0.45f, bw3 = 0.9f;

    const int tid = threadIdx.x;
    const int nchunks = (n + ELEMS_PER_BLOCK - 1) / ELEMS_PER_BLOCK;

    for (int chunk = blockIdx.x; chunk < nchunks; chunk += gridDim.x) {
        const int base = chunk * ELEMS_PER_BLOCK + tid;

        // Issue the 4 independent loads first -> 4 outstanding vmem ops.
        int   e[ELEMS_PER_THREAD];
        bool  ok[ELEMS_PER_THREAD];
        float xv[ELEMS_PER_THREAD];
        #pragma unroll
        for (int k = 0; k < ELEMS_PER_THREAD; ++k) {
            e[k]  = base + k * BLOCK;
            ok[k] = (e[k] < n);
            xv[k] = ok[k] ? x[e[k]] : 0.0f;
        }

        #pragma unroll
        for (int k = 0; k < ELEMS_PER_THREAD; ++k) {
            const float v = xv[k];

            // j = 3: bit_sum = W[9]*VREF
            bool s3 = (v >= b3);

            // j = 2: W[8]*VREF + (Q3+1)*0.5*W[7]*VR
            float b2 = b2r;
            if (s3) b2 = __fadd_rn(b2, wv7);
            bool s2 = (v >= b2);

            // j = 1: W[6]*VREF + (Q2..)*W[5]*VR + (Q3..)*W[4]*VR
            float b1 = b1r;
            if (s2) b1 = __fadd_rn(b1, wv5);
            if (s3) b1 = __fadd_rn(b1, wv4);
            bool s1 = (v >= b1);

            // j = 0: W[3]*VREF + (Q1..)*W[2]*VR + (Q2..)*W[1]*VR + (Q3..)*W[0]*VR
            float b0 = b0r;
            if (s1) b0 = __fadd_rn(b0, wv2);
            if (s2) b0 = __fadd_rn(b0, wv1);
            if (s3) b0 = __fadd_rn(b0, wv0);
            bool s0 = (v >= b0);

            // q = sum_k (Q_k+1)*0.5 * bw_k, bw_k = fl32(0.1125)*2^k
            float qv = s0 ? bw0 : 0.0f;
            if (s1) qv = __fadd_rn(qv, bw1);
            if (s2) qv = __fadd_rn(qv, bw2);
            if (s3) qv = __fadd_rn(qv, bw3);

            if (ok[k]) {
                q_out[e[k]] = qv;
                // Q[e] is 4 contiguous floats -> one float4 store,
                // 16B/lane unit-stride, fully coalesced.
                float4 Qv;
                Qv.x = s0 ? 1.0f : -1.0f;
                Qv.y = s1 ? 1.0f : -1.0f;
                Qv.z = s2 ? 1.0f : -1.0f;
                Qv.w = s3 ? 1.0f : -1.0f;
                reinterpret_cast<float4*>(Q_out)[e[k]] = Qv;
            }
        }
    }
}

extern "C" void kernel_launch(void* const* d_in, const int* in_sizes, int n_in,
                              void* d_out, int out_size, void* d_ws, size_t ws_size,
                              hipStream_t stream)
{
    const float* x = (const float*)d_in[0];   // [500000, 24] f32
    const float* W = (const float*)d_in[1];   // [10] f32
    int n = in_sizes[0];                      // 12,000,000 elements

    float* q = (float*)d_out;                 // [n] f32
    float* Q = (float*)d_out + n;             // [n, 4] f32

    const int nchunks = (n + ELEMS_PER_BLOCK - 1) / ELEMS_PER_BLOCK;
    const int grid = nchunks < 2048 ? nchunks : 2048;   // 8 blocks/CU, grid-stride
    sar_adc_kernel<<<grid, BLOCK, 0, stream>>>(x, W, q, Q, n);
}

// Round 2
// 272.755 us; speedup vs baseline: 1.0108x; 1.0108x over previous
//
#include <hip/hip_runtime.h>

// SAR-ADC 4-bit successive-approximation quantizer.
// Element-wise over N = LENGTH*NADC = 12M floats. Memory-bound:
//   read x (48 MB), write q (48 MB) + Q (192 MB) = 288 MB -> ~46 us at 6.3 TB/s.
//
// V3: decisive "best streamer" experiment. One-shot (exact grid, no
// grid-stride loop), 4 elems/thread at stride BLOCK so EVERY memory
// instruction is unit-stride across lanes (x/q: 4B/lane, Q: 16B/lane).
// Hot path has zero predication: the full/tail branch is wave-uniform
// (only the last block takes the predicated tail). Stores are batched by
// stream (4x Q dwordx4 back-to-back = 4KB/wave to one address stream,
// then 4x q dword = 1KB) for DRAM page locality, instead of interleaving
// the two store streams per element.
//
// Numerics: reference does float32 ops throughout. (Q+1)*0.5 is exactly
// 0.0 or 1.0, so each bit_sum = fl(W[m]*VREF) + subset of fl(W[k]*VR),
// added in the reference's fixed order. __fmul_rn/__fadd_rn prevent FMA
// contraction -> bit-exact thresholds -> bit-exact sign decisions.
// sign(x - b + 1e-30) == (x >= b ? +1 : -1): nonzero diffs are >= ~1e-9
// (both operands on coarse float grids), so DELTA only rescues diff==0.

#define BLOCK 256
#define EPT   4                    // elements per thread
#define EPB   (BLOCK * EPT)        // 1024 elements per block

__global__ __launch_bounds__(BLOCK)
void sar_adc_kernel(const float* __restrict__ x, const float* __restrict__ W,
                    float* __restrict__ q_out, float* __restrict__ Q_out, int n)
{
    const float VREF = 0.1125f;   // fl32(1.8/16) == fl32(0.1125)
    const float VR   = 0.1125f;

    // Wave-uniform W loads (compiler lifts to s_load), paid once per wave.
    float w0 = W[0], w1 = W[1], w2 = W[2], w3 = W[3], w4 = W[4];
    float w5 = W[5], w6 = W[6], w7 = W[7], w8 = W[8], w9 = W[9];

    // fl(W[k]*VR) terms — exactly the reference's (Q+1)*0.5*W[k]*VR when set.
    float wv0 = __fmul_rn(w0, VR);
    float wv1 = __fmul_rn(w1, VR);
    float wv2 = __fmul_rn(w2, VR);
    float wv4 = __fmul_rn(w4, VR);
    float wv5 = __fmul_rn(w5, VR);
    float wv7 = __fmul_rn(w7, VR);
    float b3  = __fmul_rn(w9, VREF);   // j=3 threshold
    float b2r = __fmul_rn(w8, VREF);   // j=2 base
    float b1r = __fmul_rn(w6, VREF);   // j=1 base
    float b0r = __fmul_rn(w3, VREF);   // j=0 base
    const float bw0 = 0.1125f, bw1 = 0.225f, bw2 = 0.45f, bw3 = 0.9f;

    const int base = blockIdx.x * EPB + threadIdx.x;
    const bool full = (blockIdx.x + 1) * EPB <= n;   // wave-uniform (scalar branch)

    float  xv[EPT];
    float  qv[EPT];
    float4 Qv[EPT];

    if (full) {
        // 4 independent unit-stride loads issued back-to-back.
        #pragma unroll
        for (int k = 0; k < EPT; ++k) xv[k] = x[base + k * BLOCK];
    } else {
        #pragma unroll
        for (int k = 0; k < EPT; ++k) {
            int e = base + k * BLOCK;
            xv[k] = (e < n) ? x[e] : 0.0f;
        }
    }

    #pragma unroll
    for (int k = 0; k < EPT; ++k) {
        const float v = xv[k];

        // j = 3: bit_sum = W[9]*VREF
        bool s3 = (v >= b3);

        // j = 2: W[8]*VREF + (Q3+1)*0.5*W[7]*VR
        float b2 = b2r;
        if (s3) b2 = __fadd_rn(b2, wv7);
        bool s2 = (v >= b2);

        // j = 1: W[6]*VREF + (Q2..)*W[5]*VR + (Q3..)*W[4]*VR
        float b1 = b1r;
        if (s2) b1 = __fadd_rn(b1, wv5);
        if (s3) b1 = __fadd_rn(b1, wv4);
        bool s1 = (v >= b1);

        // j = 0: W[3]*VREF + (Q1..)*W[2]*VR + (Q2..)*W[1]*VR + (Q3..)*W[0]*VR
        float b0 = b0r;
        if (s1) b0 = __fadd_rn(b0, wv2);
        if (s2) b0 = __fadd_rn(b0, wv1);
        if (s3) b0 = __fadd_rn(b0, wv0);
        bool s0 = (v >= b0);

        // q = sum_k (Q_k+1)*0.5 * bw_k, bw_k = fl32(0.1125)*2^k (exact)
        float qq = s0 ? bw0 : 0.0f;
        if (s1) qq = __fadd_rn(qq, bw1);
        if (s2) qq = __fadd_rn(qq, bw2);
        if (s3) qq = __fadd_rn(qq, bw3);
        qv[k] = qq;

        Qv[k].x = s0 ? 1.0f : -1.0f;
        Qv[k].y = s1 ? 1.0f : -1.0f;
        Qv[k].z = s2 ? 1.0f : -1.0f;
        Qv[k].w = s3 ? 1.0f : -1.0f;
    }

    if (full) {
        // Batch the dominant Q stream: 4 back-to-back dwordx4 stores,
        // each 16B/lane unit-stride (1KB/wave-instr, 4KB/wave total).
        #pragma unroll
        for (int k = 0; k < EPT; ++k)
            reinterpret_cast<float4*>(Q_out)[base + k * BLOCK] = Qv[k];
        // Then the q stream: 4 dword stores, 4B/lane unit-stride.
        #pragma unroll
        for (int k = 0; k < EPT; ++k)
            q_out[base + k * BLOCK] = qv[k];
    } else {
        #pragma unroll
        for (int k = 0; k < EPT; ++k) {
            int e = base + k * BLOCK;
            if (e < n) {
                reinterpret_cast<float4*>(Q_out)[e] = Qv[k];
                q_out[e] = qv[k];
            }
        }
    }
}

extern "C" void kernel_launch(void* const* d_in, const int* in_sizes, int n_in,
                              void* d_out, int out_size, void* d_ws, size_t ws_size,
                              hipStream_t stream)
{
    const float* x = (const float*)d_in[0];   // [500000, 24] f32
    const float* W = (const float*)d_in[1];   // [10] f32
    int n = in_sizes[0];                      // 12,000,000 elements

    float* q = (float*)d_out;                 // [n] f32
    float* Q = (float*)d_out + n;             // [n, 4] f32

    const int grid = (n + EPB - 1) / EPB;     // one-shot, exact cover (11719)
    sar_adc_kernel<<<grid, BLOCK, 0, stream>>>(x, W, q, Q, n);
}